// Round 1
// baseline (543.164 us; speedup 1.0000x reference)
//
#include <hip/hip_runtime.h>
#include <hip/hip_bf16.h>

// B=4, S=8192 -> 32768 tokens; HID=1024; NH=DH=32.
// Per token: q,k,v = Linear(x); scores = (q32x32 @ k32x32^T)/32; p = softmax_t;
// out[h,d] = p[h, t=d] * v[h,d]  (elementwise in flat index).
//
// Pipeline (no d_ws needed; d_out 128MB used as staging):
//  S1q: q = (query@Wq^T + bq)/32 -> bf16 at dout_b[tok*2048 + n]
//  S1k: k = (key@Wk^T + bk)      -> bf16 at dout_b[tok*2048 + 1024 + n]
//  S2 : per token, 32x32 scores via 4x mfma_16x16x32_bf16, softmax over cols,
//       rewrite token's 4KB region in-place with f32 p[h*32+t]
//  S3 : v GEMM; epilogue out[idx] = p[idx] * (v+bv)   (RMW in d_out)

typedef __attribute__((ext_vector_type(8))) short bf16x8;
typedef __attribute__((ext_vector_type(4))) float f32x4;

#define HID 1024

__device__ __forceinline__ unsigned short f2bf(float f) {
  unsigned int u = __builtin_bit_cast(unsigned int, f);
  u += 0x7FFFu + ((u >> 16) & 1u);   // RTNE
  return (unsigned short)(u >> 16);
}

// out[m,n] = sum_k X[m,k]*W[n,k] + b[n]   (torch Linear, W row-major [n][k])
// 128x128 tile, BK=32, 4 waves each 64x64, reg-staged f32->bf16, LDS rows
// padded to 80B (breaks 16-way bank alias), double-buffered, 1 barrier/iter.
template<int MODE>
__global__ __launch_bounds__(256, 2)
void gemm_kernel(const float* __restrict__ X, const float* __restrict__ W,
                 const float* __restrict__ bias, void* outp) {
  constexpr int BK = 32;
  constexpr int NKT = HID / BK;          // 32
  const int m0 = blockIdx.x * 128;
  const int n0 = blockIdx.y * 128;
  const int tid = threadIdx.x;
  const int lane = tid & 63;
  const int wid = tid >> 6;
  const int wm = (wid >> 1) << 6;        // 0 / 64
  const int wn = (wid & 1) << 6;         // 0 / 64
  const int lo = lane & 15, grp = lane >> 4;

  __shared__ __align__(16) unsigned char lds[2][2][128 * 80];  // 40KB

  const int srow = tid >> 3;             // 0..31
  const int skc  = (tid & 7) << 2;       // 0..28 step 4
  const float* Ab = X + (size_t)(m0 + srow) * HID + skc;
  const float* Bb = W + (size_t)(n0 + srow) * HID + skc;

  float4 ar[4], br[4];
  auto load_regs = [&](int ks) {
#pragma unroll
    for (int rr = 0; rr < 4; ++rr) {
      ar[rr] = *(const float4*)(Ab + (size_t)(rr * 32) * HID + ks);
      br[rr] = *(const float4*)(Bb + (size_t)(rr * 32) * HID + ks);
    }
  };
  auto write_lds = [&](int buf) {
#pragma unroll
    for (int rr = 0; rr < 4; ++rr) {
      const int off = (srow + rr * 32) * 80 + (skc << 1);
      ushort4 wa; wa.x = f2bf(ar[rr].x); wa.y = f2bf(ar[rr].y);
                  wa.z = f2bf(ar[rr].z); wa.w = f2bf(ar[rr].w);
      *(ushort4*)&lds[buf][0][off] = wa;
      ushort4 wb; wb.x = f2bf(br[rr].x); wb.y = f2bf(br[rr].y);
                  wb.z = f2bf(br[rr].z); wb.w = f2bf(br[rr].w);
      *(ushort4*)&lds[buf][1][off] = wb;
    }
  };

  f32x4 acc[4][4] = {};
  const int kbyte = grp << 4;
  auto compute = [&](int buf) {
    bf16x8 af[4], bfr[4];
#pragma unroll
    for (int f = 0; f < 4; ++f) {
      af[f]  = *(const bf16x8*)&lds[buf][0][(wm + f * 16 + lo) * 80 + kbyte];
      bfr[f] = *(const bf16x8*)&lds[buf][1][(wn + f * 16 + lo) * 80 + kbyte];
    }
#pragma unroll
    for (int fm = 0; fm < 4; ++fm)
#pragma unroll
      for (int fn = 0; fn < 4; ++fn)
        acc[fm][fn] = __builtin_amdgcn_mfma_f32_16x16x32_bf16(
            af[fm], bfr[fn], acc[fm][fn], 0, 0, 0);
  };

  load_regs(0);
  write_lds(0);
  __syncthreads();
#pragma unroll 2
  for (int kt = 0; kt < NKT; ++kt) {
    if (kt + 1 < NKT) load_regs((kt + 1) * BK);
    compute(kt & 1);
    if (kt + 1 < NKT) write_lds((kt + 1) & 1);
    __syncthreads();
  }

  // epilogue: C layout col=lane&15, row=(lane>>4)*4+j (m89-verified)
#pragma unroll
  for (int fm = 0; fm < 4; ++fm) {
    const int row = m0 + wm + fm * 16 + grp * 4;
#pragma unroll
    for (int fn = 0; fn < 4; ++fn) {
      const int col = n0 + wn + fn * 16 + lo;
      const float bc = bias[col];
#pragma unroll
      for (int j = 0; j < 4; ++j) {
        const size_t tok = (size_t)(row + j);
        const float val = acc[fm][fn][j] + bc;
        if (MODE == 0) {
          ((unsigned short*)outp)[tok * 2048 + col] = f2bf(val * 0.03125f);
        } else if (MODE == 1) {
          ((unsigned short*)outp)[tok * 2048 + 1024 + col] = f2bf(val);
        } else {
          float* of = (float*)outp;
          of[tok * 1024 + col] = of[tok * 1024 + col] * val;  // p * (v+b)
        }
      }
    }
  }
}

// S2: one wave per token. Reads q,k (bf16, 4KB) from its token region,
// computes 32x32 scores, softmax over t (cols), rewrites region with f32 p.
__global__ __launch_bounds__(256)
void attn_kernel(float* __restrict__ dout) {
  const int wid = threadIdx.x >> 6;
  const int lane = threadIdx.x & 63;
  const int token = blockIdx.x * 4 + wid;
  const int lo = lane & 15, grp = lane >> 4;
  const unsigned short* qk = (const unsigned short*)dout + (size_t)token * 2048;
  const int base = lo * 32 + grp * 8;

  // A = q_mat (rows h), B^T slot = k_mat rows t; same frag pattern both sides.
  bf16x8 a0 = *(const bf16x8*)(qk + base);          // q rows 0..15
  bf16x8 a1 = *(const bf16x8*)(qk + 512 + base);    // q rows 16..31
  bf16x8 b0 = *(const bf16x8*)(qk + 1024 + base);   // k rows 0..15
  bf16x8 b1 = *(const bf16x8*)(qk + 1536 + base);   // k rows 16..31
  // All loads must complete before we overwrite the region below.
  asm volatile("s_waitcnt vmcnt(0)" ::: "memory");

  const f32x4 z = {0.f, 0.f, 0.f, 0.f};
  f32x4 s[2][2];
  s[0][0] = __builtin_amdgcn_mfma_f32_16x16x32_bf16(a0, b0, z, 0, 0, 0);
  s[0][1] = __builtin_amdgcn_mfma_f32_16x16x32_bf16(a0, b1, z, 0, 0, 0);
  s[1][0] = __builtin_amdgcn_mfma_f32_16x16x32_bf16(a1, b0, z, 0, 0, 0);
  s[1][1] = __builtin_amdgcn_mfma_f32_16x16x32_bf16(a1, b1, z, 0, 0, 0);

  float* od = dout + (size_t)token * 1024;
#pragma unroll
  for (int rt = 0; rt < 2; ++rt) {
#pragma unroll
    for (int j = 0; j < 4; ++j) {
      const float v0 = s[rt][0][j], v1 = s[rt][1][j];
      float m = fmaxf(v0, v1);
#pragma unroll
      for (int msk = 1; msk < 16; msk <<= 1) m = fmaxf(m, __shfl_xor(m, msk, 64));
      const float e0 = __expf(v0 - m), e1 = __expf(v1 - m);
      float ssum = e0 + e1;
#pragma unroll
      for (int msk = 1; msk < 16; msk <<= 1) ssum += __shfl_xor(ssum, msk, 64);
      const float inv = 1.0f / ssum;
      const int h = rt * 16 + grp * 4 + j;          // row (m89 C layout)
      od[h * 32 + lo]      = e0 * inv;              // t = lo
      od[h * 32 + 16 + lo] = e1 * inv;              // t = 16+lo
    }
  }
}

extern "C" void kernel_launch(void* const* d_in, const int* in_sizes, int n_in,
                              void* d_out, int out_size, void* d_ws, size_t ws_size,
                              hipStream_t stream) {
  const float* query = (const float*)d_in[0];
  const float* key   = (const float*)d_in[1];
  const float* value = (const float*)d_in[2];
  const float* Wq    = (const float*)d_in[3];
  const float* bq    = (const float*)d_in[4];
  const float* Wk    = (const float*)d_in[5];
  const float* bk    = (const float*)d_in[6];
  const float* Wv    = (const float*)d_in[7];
  const float* bv    = (const float*)d_in[8];

  dim3 grid(256, 8), block(256);
  gemm_kernel<0><<<grid, block, 0, stream>>>(query, Wq, bq, d_out);
  gemm_kernel<1><<<grid, block, 0, stream>>>(key,   Wk, bk, d_out);
  attn_kernel<<<dim3(8192), dim3(256), 0, stream>>>((float*)d_out);
  gemm_kernel<2><<<grid, block, 0, stream>>>(value, Wv, bv, d_out);
}

// Round 2
// 493.359 us; speedup vs baseline: 1.1010x; 1.1010x over previous
//
#include <hip/hip_runtime.h>
#include <hip/hip_bf16.h>

// B=4, S=8192 -> 32768 tokens; HID=1024; NH=DH=32.
// S1q: q=(query@Wq^T+bq)/32 -> bf16 @ dout_b[tok*2048 + n]
// S1k: k=(key@Wk^T+bk)      -> bf16 @ dout_b[tok*2048 + 1024 + n]
// S2 : per-token 32x32 scores + softmax over heads-t, rewrite region w/ f32 p
// S3 : v GEMM; epilogue out[idx] = p[idx] * (v+bv)  (f32 RMW in d_out)

typedef __attribute__((ext_vector_type(8))) short bf16x8;
typedef __attribute__((ext_vector_type(4))) float f32x4;

#define HID 1024

#define GLOAD_LDS16(gp, lp)                                                   \
  __builtin_amdgcn_global_load_lds(                                           \
      (const __attribute__((address_space(1))) void*)(gp),                    \
      (__attribute__((address_space(3))) void*)(lp), 16, 0, 0)

__device__ __forceinline__ unsigned short f2bf(float f) {
  unsigned int u = __builtin_bit_cast(unsigned int, f);
  u += 0x7FFFu + ((u >> 16) & 1u);  // RTNE
  return (unsigned short)(u >> 16);
}

// 8 consecutive f32 (two 16B regs) -> bf16x8 via v_cvt_pk_bf16_f32
__device__ __forceinline__ bf16x8 cvt8(f32x4 a, f32x4 b) {
  union { unsigned int u[4]; bf16x8 v; } r;
  asm("v_cvt_pk_bf16_f32 %0, %1, %2" : "=v"(r.u[0]) : "v"(a[0]), "v"(a[1]));
  asm("v_cvt_pk_bf16_f32 %0, %1, %2" : "=v"(r.u[1]) : "v"(a[2]), "v"(a[3]));
  asm("v_cvt_pk_bf16_f32 %0, %1, %2" : "=v"(r.u[2]) : "v"(b[0]), "v"(b[1]));
  asm("v_cvt_pk_bf16_f32 %0, %1, %2" : "=v"(r.u[3]) : "v"(b[2]), "v"(b[3]));
  return r.v;
}

// out[m,n] = sum_k X[m,k]*W[n,k] + b[n]. 128x128 tile, BK=32, m97 2-barrier
// structure: global_load_lds f32 tiles (XOR-swizzled via pre-swizzled global
// source, LDS linear), cvt to bf16 at fragment read. 32KB LDS single buffer.
template<int MODE>
__global__ __launch_bounds__(256, 4)
void gemm_kernel(const float* __restrict__ X, const float* __restrict__ W,
                 const float* __restrict__ bias, void* outp) {
  // XCD-chunked swizzle: grid 2048 = 256 m-tiles x 8 n-tiles, n fastest
  const int bid = blockIdx.x;
  const int L = (bid & 7) * 256 + (bid >> 3);
  const int m0 = (L >> 3) * 128;
  const int n0 = (L & 7) * 128;
  const int tid = threadIdx.x;
  const int lane = tid & 63;
  const int wid = tid >> 6;
  const int wm = (wid >> 1) << 6;
  const int wn = (wid & 1) << 6;
  const int lo = lane & 15, grp = lane >> 4;

  // A f32 [128][32] bytes 0..16K, B at 16K..32K. LDS linear; logical layout
  // byte(row,kb) = row*128 + (kb ^ ((row&7)<<4)).
  __shared__ __align__(16) unsigned char lds[32768];

  const int srow8 = lane >> 3;                       // row&7 for this lane
  const int scol = (((lane & 7) ^ srow8) << 2);      // pre-swizzled float col

  f32x4 acc[4][4] = {};

  const unsigned char* ldsc = lds;
#pragma unroll 1
  for (int k0 = 0; k0 < HID; k0 += 32) {
#pragma unroll
    for (int it = 0; it < 4; ++it) {
      const int c = it * 4 + wid;                    // 16 row-chunks of 8
      const int r = c * 8 + srow8;
      GLOAD_LDS16(X + (size_t)(m0 + r) * HID + k0 + scol, lds + c * 1024);
      GLOAD_LDS16(W + (size_t)(n0 + r) * HID + k0 + scol, lds + 16384 + c * 1024);
    }
    __syncthreads();  // drains vmcnt(0): tiles resident

    bf16x8 af[4], bf[4];
#pragma unroll
    for (int f = 0; f < 4; ++f) {
      {
        const int row = wm + f * 16 + lo;
        const int xr = (row & 7) << 4;
        const f32x4 a0 = *(const f32x4*)&ldsc[row * 128 + ((grp * 32) ^ xr)];
        const f32x4 a1 = *(const f32x4*)&ldsc[row * 128 + ((grp * 32 + 16) ^ xr)];
        af[f] = cvt8(a0, a1);
      }
      {
        const int row = wn + f * 16 + lo;
        const int xr = (row & 7) << 4;
        const f32x4 b0 = *(const f32x4*)&ldsc[16384 + row * 128 + ((grp * 32) ^ xr)];
        const f32x4 b1 = *(const f32x4*)&ldsc[16384 + row * 128 + ((grp * 32 + 16) ^ xr)];
        bf[f] = cvt8(b0, b1);
      }
    }
#pragma unroll
    for (int fm = 0; fm < 4; ++fm)
#pragma unroll
      for (int fn = 0; fn < 4; ++fn)
        acc[fm][fn] = __builtin_amdgcn_mfma_f32_16x16x32_bf16(
            af[fm], bf[fn], acc[fm][fn], 0, 0, 0);
    __syncthreads();  // tile consumed; safe to restage
  }

  // Epilogue. C layout: col=lane&15, row=(lane>>4)*4+j (m89-verified).
  if (MODE == 2) {
    float* of = (float*)outp;
#pragma unroll
    for (int fm = 0; fm < 4; ++fm) {
      const int row = m0 + wm + fm * 16 + grp * 4;
#pragma unroll
      for (int fn = 0; fn < 4; ++fn) {
        const int col = n0 + wn + fn * 16 + lo;
        const float bc = bias[col];
#pragma unroll
        for (int j = 0; j < 4; ++j) {
          const size_t tok = (size_t)(row + j);
          of[tok * 1024 + col] = of[tok * 1024 + col] * (acc[fm][fn][j] + bc);
        }
      }
    }
  } else {
    // Stage bf16 result in LDS (swizzled), then 256B-contiguous row writes.
    const float scale = (MODE == 0) ? 0.03125f : 1.0f;
#pragma unroll
    for (int fm = 0; fm < 4; ++fm) {
#pragma unroll
      for (int fn = 0; fn < 4; ++fn) {
        const int colL = wn + fn * 16 + lo;
        const float bc = bias[n0 + colL];
#pragma unroll
        for (int j = 0; j < 4; ++j) {
          const int rowL = wm + fm * 16 + grp * 4 + j;
          const int byte = rowL * 256 + ((colL * 2) ^ ((rowL & 7) << 5));
          *(unsigned short*)&lds[byte] = f2bf((acc[fm][fn][j] + bc) * scale);
        }
      }
    }
    __syncthreads();
    unsigned short* ob = (unsigned short*)outp;
    const int half = (MODE == 1) ? 1024 : 0;
#pragma unroll
    for (int p = 0; p < 8; ++p) {
      const int r = p * 16 + (tid >> 4);
      const int c0 = (tid & 15) * 8;
      const uint4 v = *(const uint4*)&ldsc[r * 256 + ((c0 * 2) ^ ((r & 7) << 5))];
      *(uint4*)&ob[(size_t)(m0 + r) * 2048 + half + n0 + c0] = v;
    }
  }
}

// S2: one wave per token. 32x32 scores via 4 MFMA, softmax over t (cols),
// rewrite token's 4KB region with f32 p[h*32+t].
__global__ __launch_bounds__(256)
void attn_kernel(float* __restrict__ dout) {
  const int wid = threadIdx.x >> 6;
  const int lane = threadIdx.x & 63;
  const int token = blockIdx.x * 4 + wid;
  const int lo = lane & 15, grp = lane >> 4;
  const unsigned short* qk = (const unsigned short*)dout + (size_t)token * 2048;
  const int base = lo * 32 + grp * 8;

  bf16x8 a0 = *(const bf16x8*)(qk + base);          // q rows 0..15
  bf16x8 a1 = *(const bf16x8*)(qk + 512 + base);    // q rows 16..31
  bf16x8 b0 = *(const bf16x8*)(qk + 1024 + base);   // k rows 0..15
  bf16x8 b1 = *(const bf16x8*)(qk + 1536 + base);   // k rows 16..31
  asm volatile("s_waitcnt vmcnt(0)" ::: "memory");  // loads before overwrite

  const f32x4 z = {0.f, 0.f, 0.f, 0.f};
  f32x4 s[2][2];
  s[0][0] = __builtin_amdgcn_mfma_f32_16x16x32_bf16(a0, b0, z, 0, 0, 0);
  s[0][1] = __builtin_amdgcn_mfma_f32_16x16x32_bf16(a0, b1, z, 0, 0, 0);
  s[1][0] = __builtin_amdgcn_mfma_f32_16x16x32_bf16(a1, b0, z, 0, 0, 0);
  s[1][1] = __builtin_amdgcn_mfma_f32_16x16x32_bf16(a1, b1, z, 0, 0, 0);

  float* od = dout + (size_t)token * 1024;
#pragma unroll
  for (int rt = 0; rt < 2; ++rt) {
#pragma unroll
    for (int j = 0; j < 4; ++j) {
      const float v0 = s[rt][0][j], v1 = s[rt][1][j];
      float m = fmaxf(v0, v1);
#pragma unroll
      for (int msk = 1; msk < 16; msk <<= 1) m = fmaxf(m, __shfl_xor(m, msk, 64));
      const float e0 = __expf(v0 - m), e1 = __expf(v1 - m);
      float ssum = e0 + e1;
#pragma unroll
      for (int msk = 1; msk < 16; msk <<= 1) ssum += __shfl_xor(ssum, msk, 64);
      const float inv = 1.0f / ssum;
      const int h = rt * 16 + grp * 4 + j;
      od[h * 32 + lo]      = e0 * inv;
      od[h * 32 + 16 + lo] = e1 * inv;
    }
  }
}

extern "C" void kernel_launch(void* const* d_in, const int* in_sizes, int n_in,
                              void* d_out, int out_size, void* d_ws, size_t ws_size,
                              hipStream_t stream) {
  const float* query = (const float*)d_in[0];
  const float* key   = (const float*)d_in[1];
  const float* value = (const float*)d_in[2];
  const float* Wq    = (const float*)d_in[3];
  const float* bq    = (const float*)d_in[4];
  const float* Wk    = (const float*)d_in[5];
  const float* bk    = (const float*)d_in[6];
  const float* Wv    = (const float*)d_in[7];
  const float* bv    = (const float*)d_in[8];

  gemm_kernel<0><<<dim3(2048), dim3(256), 0, stream>>>(query, Wq, bq, d_out);
  gemm_kernel<1><<<dim3(2048), dim3(256), 0, stream>>>(key,   Wk, bk, d_out);
  attn_kernel<<<dim3(8192), dim3(256), 0, stream>>>((float*)d_out);
  gemm_kernel<2><<<dim3(2048), dim3(256), 0, stream>>>(value, Wv, bv, d_out);
}